// Round 1
// baseline (360.304 us; speedup 1.0000x reference)
//
#include <hip/hip_runtime.h>

typedef unsigned short u16;
typedef __bf16 bf16x8 __attribute__((ext_vector_type(8)));
typedef float f32x4 __attribute__((ext_vector_type(4)));

#define T_SEQ 2048
#define NH 16
#define HD 64
#define CDIM 1024
#define BDIM 4

__device__ __forceinline__ u16 f2bf(float f) {
    union { float f; unsigned int u; } v; v.f = f;
    unsigned int r = v.u + 0x7FFFu + ((v.u >> 16) & 1u);
    return (u16)(r >> 16);
}

// ---------------- cast fp32 -> bf16 ----------------
__global__ void cast_f32_bf16(const float* __restrict__ in, u16* __restrict__ out, int n) {
    int i = (blockIdx.x * blockDim.x + threadIdx.x) * 4;
    if (i >= n) return;
    float4 v = *reinterpret_cast<const float4*>(in + i);
    ushort4 o;
    o.x = f2bf(v.x); o.y = f2bf(v.y); o.z = f2bf(v.z); o.w = f2bf(v.w);
    *reinterpret_cast<ushort4*>(out + i) = o;
}

// ---------------- transpose + cast: in [K][N] fp32 -> out [N][K] bf16 ----------------
__global__ void transpose_cast(const float* __restrict__ in, u16* __restrict__ out, int K, int N) {
    __shared__ float tile[32][33];
    int n0 = blockIdx.x * 32, k0 = blockIdx.y * 32;
    int tx = threadIdx.x & 31, ty = threadIdx.x >> 5;  // 32 x 8
#pragma unroll
    for (int i = 0; i < 32; i += 8)
        tile[ty + i][tx] = in[(size_t)(k0 + ty + i) * N + n0 + tx];
    __syncthreads();
#pragma unroll
    for (int i = 0; i < 32; i += 8)
        out[(size_t)(n0 + ty + i) * K + k0 + tx] = f2bf(tile[tx][ty + i]);
}

// ---------------- GEMM: C[M][N] = A[M][K](bf16) * Bt[N][K](bf16)^T + bias ----------------
// EPI=0: scatter qkv epilogue -> Qb/Kb [BH][T][D] bf16, Vt [BH][D][T] bf16
// EPI=1: fp32 epilogue -> out [M][N]
template <int EPI>
__global__ __launch_bounds__(256, 2)
void gemm_bt(const u16* __restrict__ A, const u16* __restrict__ Bt,
             const float* __restrict__ bias, float* __restrict__ out,
             u16* __restrict__ qb, u16* __restrict__ kb, u16* __restrict__ vtb,
             int M, int N, int K) {
    __shared__ u16 As[128][40];
    __shared__ u16 Bs[128][40];
    const int tid = threadIdx.x;
    const int lane = tid & 63;
    const int w = tid >> 6;
    const int wm = w >> 1, wn = w & 1;
    const int gm0 = blockIdx.y * 128;
    const int gn0 = blockIdx.x * 128;

    f32x4 acc[4][4] = {};

    for (int k0 = 0; k0 < K; k0 += 32) {
#pragma unroll
        for (int it = 0; it < 2; ++it) {
            int task = tid + it * 256;
            int r = task >> 2;
            int cc = (task & 3) << 3;
            *reinterpret_cast<uint4*>(&As[r][cc]) =
                *reinterpret_cast<const uint4*>(&A[(size_t)(gm0 + r) * K + k0 + cc]);
            *reinterpret_cast<uint4*>(&Bs[r][cc]) =
                *reinterpret_cast<const uint4*>(&Bt[(size_t)(gn0 + r) * K + k0 + cc]);
        }
        __syncthreads();
        bf16x8 a[4], b[4];
#pragma unroll
        for (int m = 0; m < 4; ++m)
            a[m] = *reinterpret_cast<const bf16x8*>(&As[wm * 64 + m * 16 + (lane & 15)][(lane >> 4) * 8]);
#pragma unroll
        for (int n = 0; n < 4; ++n)
            b[n] = *reinterpret_cast<const bf16x8*>(&Bs[wn * 64 + n * 16 + (lane & 15)][(lane >> 4) * 8]);
#pragma unroll
        for (int m = 0; m < 4; ++m)
#pragma unroll
            for (int n = 0; n < 4; ++n)
                acc[m][n] = __builtin_amdgcn_mfma_f32_16x16x32_bf16(a[m], b[n], acc[m][n], 0, 0, 0);
        __syncthreads();
    }

#pragma unroll
    for (int m = 0; m < 4; ++m) {
#pragma unroll
        for (int n = 0; n < 4; ++n) {
            int gcol = gn0 + wn * 64 + n * 16 + (lane & 15);
            float bv = bias[gcol];
#pragma unroll
            for (int r = 0; r < 4; ++r) {
                int grow = gm0 + wm * 64 + m * 16 + (lane >> 4) * 4 + r;
                float v = acc[m][n][r] + bv;
                if (EPI == 1) {
                    out[(size_t)grow * N + gcol] = v;
                } else {
                    int which = gcol >> 10;
                    int c = gcol & 1023;
                    int h = c >> 6, d = c & 63;
                    int b_ = grow >> 11, t = grow & 2047;
                    int bh = b_ * NH + h;
                    u16 bvv = f2bf(v);
                    if (which == 0)      qb[((size_t)bh * T_SEQ + t) * HD + d] = bvv;
                    else if (which == 1) kb[((size_t)bh * T_SEQ + t) * HD + d] = bvv;
                    else                 vtb[((size_t)bh * HD + d) * T_SEQ + t] = bvv;
                }
            }
        }
    }
}

// ---------------- flash attention (causal) ----------------
// Qb/Kb: [BH][T][64] bf16 ; Vt: [BH][64][T] bf16 ; yb out: [B][T][C] bf16
__global__ __launch_bounds__(256, 2)
void attn_fwd(const u16* __restrict__ Qb, const u16* __restrict__ Kb,
              const u16* __restrict__ Vt, u16* __restrict__ yb) {
    __shared__ u16 Ks[64][72];
    __shared__ u16 Vs[64][72];
    __shared__ u16 Ps[4][16][72];
    const int tid = threadIdx.x, lane = tid & 63, w = tid >> 6;
    const int qt = blockIdx.x, bh = blockIdx.y;
    const int b = bh >> 4, h = bh & 15;
    const int q0 = qt * 64;
    const int qw = q0 + w * 16;
    const float CS = 0.125f * 1.44269504088896340736f;  // 1/sqrt(64) * log2(e)

    // Q fragments (2 k-halves of D=64)
    const u16* qrow = &Qb[((size_t)bh * T_SEQ + qw + (lane & 15)) * HD];
    bf16x8 aq0 = *reinterpret_cast<const bf16x8*>(qrow + ((lane >> 4) * 8));
    bf16x8 aq1 = *reinterpret_cast<const bf16x8*>(qrow + 32 + ((lane >> 4) * 8));

    f32x4 yacc[4] = {};
    float mrun[4] = {-1e30f, -1e30f, -1e30f, -1e30f};
    float lrun[4] = {0.f, 0.f, 0.f, 0.f};

    const int nt = qt + 1;
    for (int kt = 0; kt < nt; ++kt) {
        const int kv0 = kt * 64;
        __syncthreads();
#pragma unroll
        for (int it = 0; it < 2; ++it) {
            int task = tid + it * 256;
            int r = task >> 3, cc = (task & 7) << 3;
            *reinterpret_cast<uint4*>(&Ks[r][cc]) =
                *reinterpret_cast<const uint4*>(&Kb[((size_t)bh * T_SEQ + kv0 + r) * HD + cc]);
            *reinterpret_cast<uint4*>(&Vs[r][cc]) =
                *reinterpret_cast<const uint4*>(&Vt[((size_t)bh * HD + r) * T_SEQ + kv0 + cc]);
        }
        __syncthreads();

        // S = Q K^T
        f32x4 s[4];
#pragma unroll
        for (int n = 0; n < 4; ++n) {
            bf16x8 b0 = *reinterpret_cast<const bf16x8*>(&Ks[n * 16 + (lane & 15)][(lane >> 4) * 8]);
            bf16x8 b1 = *reinterpret_cast<const bf16x8*>(&Ks[n * 16 + (lane & 15)][32 + (lane >> 4) * 8]);
            f32x4 t = {};
            t = __builtin_amdgcn_mfma_f32_16x16x32_bf16(aq0, b0, t, 0, 0, 0);
            t = __builtin_amdgcn_mfma_f32_16x16x32_bf16(aq1, b1, t, 0, 0, 0);
            s[n] = t;
        }
        // causal mask (only tiles crossing the diagonal for this wave)
        if (kv0 + 63 > qw) {
            const int qrb = qw + (lane >> 4) * 4;
#pragma unroll
            for (int n = 0; n < 4; ++n) {
                int col = kv0 + n * 16 + (lane & 15);
#pragma unroll
                for (int r = 0; r < 4; ++r)
                    if (col > qrb + r) s[n][r] = -INFINITY;
            }
        }
        // online softmax (rows split 4/lane, shared across 16-lane groups)
        float al[4];
#pragma unroll
        for (int r = 0; r < 4; ++r) {
            float v = fmaxf(fmaxf(s[0][r], s[1][r]), fmaxf(s[2][r], s[3][r]));
            v = fmaxf(v, __shfl_xor(v, 1));
            v = fmaxf(v, __shfl_xor(v, 2));
            v = fmaxf(v, __shfl_xor(v, 4));
            v = fmaxf(v, __shfl_xor(v, 8));
            float mn = fmaxf(mrun[r], v);
            al[r] = __builtin_amdgcn_exp2f((mrun[r] - mn) * CS);
            mrun[r] = mn;
        }
        float rs[4] = {0.f, 0.f, 0.f, 0.f};
#pragma unroll
        for (int n = 0; n < 4; ++n)
#pragma unroll
            for (int r = 0; r < 4; ++r) {
                float p = __builtin_amdgcn_exp2f((s[n][r] - mrun[r]) * CS);
                s[n][r] = p;
                rs[r] += p;
            }
#pragma unroll
        for (int r = 0; r < 4; ++r) {
            float v = rs[r];
            v += __shfl_xor(v, 1);
            v += __shfl_xor(v, 2);
            v += __shfl_xor(v, 4);
            v += __shfl_xor(v, 8);
            lrun[r] = lrun[r] * al[r] + v;
#pragma unroll
            for (int n = 0; n < 4; ++n) yacc[n][r] *= al[r];
        }
        // P -> LDS (re-layout for A-fragment)
#pragma unroll
        for (int n = 0; n < 4; ++n)
#pragma unroll
            for (int r = 0; r < 4; ++r)
                Ps[w][(lane >> 4) * 4 + r][n * 16 + (lane & 15)] = f2bf(s[n][r]);
        __syncthreads();
        // y += P V
        bf16x8 pa0 = *reinterpret_cast<const bf16x8*>(&Ps[w][lane & 15][(lane >> 4) * 8]);
        bf16x8 pa1 = *reinterpret_cast<const bf16x8*>(&Ps[w][lane & 15][32 + (lane >> 4) * 8]);
#pragma unroll
        for (int n = 0; n < 4; ++n) {
            bf16x8 bv0 = *reinterpret_cast<const bf16x8*>(&Vs[n * 16 + (lane & 15)][(lane >> 4) * 8]);
            bf16x8 bv1 = *reinterpret_cast<const bf16x8*>(&Vs[n * 16 + (lane & 15)][32 + (lane >> 4) * 8]);
            yacc[n] = __builtin_amdgcn_mfma_f32_16x16x32_bf16(pa0, bv0, yacc[n], 0, 0, 0);
            yacc[n] = __builtin_amdgcn_mfma_f32_16x16x32_bf16(pa1, bv1, yacc[n], 0, 0, 0);
        }
    }
    // write y (bf16, [B][T][C] with c = h*64 + d)
#pragma unroll
    for (int r = 0; r < 4; ++r) {
        float inv = 1.0f / lrun[r];
        int q = qw + (lane >> 4) * 4 + r;
#pragma unroll
        for (int n = 0; n < 4; ++n) {
            int c = h * HD + n * 16 + (lane & 15);
            yb[((size_t)b * T_SEQ + q) * CDIM + c] = f2bf(yacc[n][r] * inv);
        }
    }
}

extern "C" void kernel_launch(void* const* d_in, const int* in_sizes, int n_in,
                              void* d_out, int out_size, void* d_ws, size_t ws_size,
                              hipStream_t stream) {
    const float* x      = (const float*)d_in[0];
    const float* w_attn = (const float*)d_in[1];
    const float* b_attn = (const float*)d_in[2];
    const float* w_proj = (const float*)d_in[3];
    const float* b_proj = (const float*)d_in[4];
    float* out = (float*)d_out;

    u16* ws  = (u16*)d_ws;
    u16* xb  = ws;                                    // 8192*1024
    u16* wT  = xb  + (size_t)8192 * 1024;             // 3072*1024
    u16* wpT = wT  + (size_t)3072 * 1024;             // 1024*1024
    u16* Qb  = wpT + (size_t)1024 * 1024;             // 64*2048*64
    u16* Kb  = Qb  + (size_t)64 * 2048 * 64;
    u16* Vt  = Kb  + (size_t)64 * 2048 * 64;
    u16* yb  = Vt  + (size_t)64 * 2048 * 64;          // 8192*1024

    cast_f32_bf16<<<8192, 256, 0, stream>>>(x, xb, 8192 * 1024);
    transpose_cast<<<dim3(96, 32), 256, 0, stream>>>(w_attn, wT, 1024, 3072);
    transpose_cast<<<dim3(32, 32), 256, 0, stream>>>(w_proj, wpT, 1024, 1024);
    gemm_bt<0><<<dim3(24, 64), 256, 0, stream>>>(xb, wT, b_attn, nullptr, Qb, Kb, Vt,
                                                 8192, 3072, 1024);
    attn_fwd<<<dim3(32, 64), 256, 0, stream>>>(Qb, Kb, Vt, yb);
    gemm_bt<1><<<dim3(8, 64), 256, 0, stream>>>(yb, wpT, b_proj, out, nullptr, nullptr, nullptr,
                                                8192, 1024, 1024);
}